// Round 13
// baseline (1299.991 us; speedup 1.0000x reference)
//
#include <hip/hip_runtime.h>
#include <hip/hip_bf16.h>
#include <math.h>

#define N_NODES 50000
#define NPAD    50048                  // N_NODES rounded up to 128 (gemm tiles, no guards)
#define N_EDGES 800000
#define EPRIME  (N_EDGES + N_NODES)   // edges + self loops
#define HEADS 8
#define CH 64
#define FDIM 512                       // HEADS*CH

typedef unsigned short ushort_t;
typedef __attribute__((ext_vector_type(8))) short bf16x8_t;  // 8 bf16 = 4 VGPRs
typedef __attribute__((ext_vector_type(4))) float f32x4_t;

__device__ __forceinline__ float bf2f(unsigned short u) {
  union { unsigned int i; float f; } v; v.i = ((unsigned int)u) << 16; return v.f;
}
__device__ __forceinline__ unsigned short f2bf(float f) {
  union { float f; unsigned int i; } v; v.f = f;
  unsigned int x = v.i;
  return (unsigned short)((x + 0x7fffu + ((x >> 16) & 1u)) >> 16);  // RNE
}
__device__ __forceinline__ float ldf(const void* p, size_t idx, int isf32) {
  return isf32 ? ((const float*)p)[idx] : bf2f(((const ushort_t*)p)[idx]);
}
__device__ __forceinline__ void stf(void* p, size_t idx, float v, int isf32) {
  if (isf32) ((float*)p)[idx] = v;
  else       ((ushort_t*)p)[idx] = f2bf(v);
}
__device__ __forceinline__ float leakyf(float v) { return v >= 0.f ? v : 0.2f * v; }
__device__ __forceinline__ float eluf(float v)   { return v > 0.f ? v : expm1f(v); }

// async global->LDS, 16B per lane; LDS dest = wave-uniform base + lane*16
typedef const __attribute__((address_space(1))) unsigned int* gas1_t;
typedef __attribute__((address_space(3))) unsigned int* las3_t;
__device__ __forceinline__ void gll16(const ushort_t* g, ushort_t* l) {
  __builtin_amdgcn_global_load_lds((gas1_t)g, (las3_t)l, 16, 0, 0);
}

// ---------------- dtype detector ----------------
__global__ void detect_dtype(const void* Wn, int* flag) {
  if (blockIdx.x == 0 && threadIdx.x == 0) {
    const ushort_t* u = (const ushort_t*)Wn;
    int extreme = 0;
    for (int i = 0; i < 384; ++i) {
      float v = fabsf(bf2f(u[i]));
      if (v != 0.f && (v > 16.f || v < 6.1e-5f)) extreme++;
    }
    *flag = (extreme >= 20) ? 1 : 0;
  }
}

// ---------------- layer-1 fold: Wf[0..2][512] = Wn^T-fold, Wf[3][512] = bn@W1 --
__global__ void fold_w1(const void* __restrict__ Wn, const void* __restrict__ bn,
                        const void* __restrict__ W1, float* __restrict__ Wf,
                        const int* __restrict__ dflag) {
  int isf32 = *dflag;
  int c = blockIdx.x * blockDim.x + threadIdx.x;
  if (c >= 512) return;
  #pragma unroll
  for (int r = 0; r < 3; ++r) {
    float s = 0.f;
    for (int k = 0; k < 64; ++k)
      s += ldf(Wn, r * 64 + k, isf32) * ldf(W1, k * 512 + c, isf32);
    Wf[r * 512 + c] = s;
  }
  float s = 0.f;
  for (int k = 0; k < 64; ++k)
    s += ldf(bn, k, isf32) * ldf(W1, k * 512 + c, isf32);
  Wf[3 * 512 + c] = s;
}

// ---------------- weight transpose-convert: dst[n*K+k] = src[(boff+k)*N + n] ----
__global__ void convert_wt(const void* __restrict__ src, ushort_t* __restrict__ dst,
                           int K, int N, int boff, const int* __restrict__ dflag) {
  int isf32 = *dflag;
  int tid = blockIdx.x * blockDim.x + threadIdx.x;
  if (tid >= N * K) return;
  int n = tid / K, k = tid % K;
  dst[tid] = f2bf(ldf(src, (size_t)(boff + k) * N + n, isf32));
}

// pack 6 attention vectors (3 layers x {a_src, a_dst}, 512 elems each) to bf16
__global__ void convert_att(const void* s1, const void* d1, const void* s2, const void* d2,
                            const void* s3, const void* d3, ushort_t* __restrict__ dst,
                            const int* __restrict__ dflag) {
  int isf32 = *dflag;
  int tid = blockIdx.x * blockDim.x + threadIdx.x;
  if (tid >= 6 * 512) return;
  int which = tid >> 9, idx = tid & 511;
  const void* p = which == 0 ? s1 : which == 1 ? d1 : which == 2 ? s2
                : which == 3 ? d2 : which == 4 ? s3 : d3;
  dst[tid] = f2bf(ldf(p, idx, isf32));
}

// ---------------- CSR build ----------------
__global__ void init_deg(int* deg, int* fill) {
  int n = blockIdx.x * blockDim.x + threadIdx.x;
  if (n < N_NODES) { deg[n] = 1; fill[n] = 0; }   // 1 = self loop
}

__global__ void count_edges(const int* __restrict__ ei, int* deg) {
  int e = blockIdx.x * blockDim.x + threadIdx.x;
  if (e < N_EDGES) atomicAdd(&deg[ei[N_EDGES + e]], 1);
}

__global__ void scan64(const int* __restrict__ deg, int* __restrict__ rowptr) {
  const int CHUNK = (N_NODES + 63) / 64;   // 782
  int t = threadIdx.x;
  int lo = t * CHUNK;
  int hi = lo + CHUNK; if (hi > N_NODES) hi = N_NODES;
  int s = 0;
  for (int i = lo; i < hi; ++i) s += deg[i];
  int inc = s;
  #pragma unroll
  for (int off = 1; off < 64; off <<= 1) {
    int u = __shfl_up(inc, off);
    if (t >= off) inc += u;
  }
  int run = inc - s;
  for (int i = lo; i < hi; ++i) { rowptr[i] = run; run += deg[i]; }
  if (t == 63) rowptr[N_NODES] = run;
}

__global__ void fill_csr(const int* __restrict__ ei, const int* __restrict__ rowptr,
                         int* fill, int* __restrict__ csr_src) {
  int e = blockIdx.x * blockDim.x + threadIdx.x;
  if (e >= EPRIME) return;
  int s, d;
  if (e < N_EDGES) { s = ei[e]; d = ei[N_EDGES + e]; }
  else             { s = d = e - N_EDGES; }
  int pos = rowptr[d] + atomicAdd(&fill[d], 1);
  csr_src[pos] = s;
}

// ---------------- layer-1 direct: g1 = x@Wf + bfold, fused attn reduce --------
// 2 nodes/block; thread tl (0..127): channels 4tl..4tl+3, head tl>>4.
__global__ __launch_bounds__(256) void encode_g1(
    const void* __restrict__ x, const float* __restrict__ Wf,
    const ushort_t* __restrict__ att, ushort_t* __restrict__ g,
    float* __restrict__ asrc, float* __restrict__ dstat,
    const int* __restrict__ dflag) {
  int isf32 = *dflag;
  int t = threadIdx.x;
  int half = t >> 7;
  int n = blockIdx.x * 2 + half;           // N_NODES even
  int tl = t & 127;
  int c0 = tl * 4;
  int head = tl >> 4;
  __shared__ float sx[2][3];
  if (tl < 3) sx[half][tl] = ldf(x, n * 3 + tl, isf32);
  __syncthreads();
  float x0 = sx[half][0], x1 = sx[half][1], x2 = sx[half][2];
  float ss = 0.f, dd = 0.f;
  ushort4 ov;
  ushort_t* ovp = (ushort_t*)&ov;
  #pragma unroll
  for (int j = 0; j < 4; ++j) {
    int c = c0 + j;
    float v = x0 * Wf[c] + x1 * Wf[512 + c] + x2 * Wf[1024 + c] + Wf[1536 + c];
    ushort_t uv = f2bf(v);
    ovp[j] = uv;
    float cv = bf2f(uv);
    ss += cv * bf2f(att[head * CH + (c & 63)]);
    dd += cv * bf2f(att[512 + head * CH + (c & 63)]);
  }
  *(ushort4*)(g + (size_t)n * FDIM + c0) = ov;
  #pragma unroll
  for (int off = 8; off >= 1; off >>= 1) {
    ss += __shfl_down(ss, off);
    dd += __shfl_down(dd, off);
  }
  if ((tl & 15) == 0) {
    asrc[n * HEADS + head] = ss;
    dstat[2 * (n * HEADS + head)] = dd;
  }
}

// ---------------- MFMA GEMM + fused attn-coef epilogue ------------------------
// C = A @ BT^T.  When att != nullptr, wave covers one head = 2*by + wc; epilogue
// computes asrc / dstat.x via 16-lane reduce.
__global__ __launch_bounds__(256) void gemm_bt(
    const ushort_t* __restrict__ A, const ushort_t* __restrict__ BT,
    ushort_t* __restrict__ C, int K, int ldc,
    const ushort_t* __restrict__ att, float* __restrict__ asrc, float* __restrict__ dstat)
{
  __shared__ __align__(16) ushort_t As[128][32];
  __shared__ __align__(16) ushort_t Bs[128][32];
  int tid = threadIdx.x;
  int wave = tid >> 6, lane = tid & 63;
  int wr = wave >> 1, wc = wave & 1;
  int row0 = blockIdx.x * 128, col0 = blockIdx.y * 128;
  int fm = lane & 15, fq = lane >> 4;

  f32x4_t acc[4][4];
  #pragma unroll
  for (int i = 0; i < 4; ++i)
    #pragma unroll
    for (int j = 0; j < 4; ++j) acc[i][j] = (f32x4_t){0.f, 0.f, 0.f, 0.f};

  int srow = wave * 32 + (lane >> 2);
  int skel = (lane & 3) * 8;
  const ushort_t* aG0 = A  + (size_t)(row0 + srow) * K + skel;
  const ushort_t* aG1 = A  + (size_t)(row0 + srow + 16) * K + skel;
  const ushort_t* bG0 = BT + (size_t)(col0 + srow) * K + skel;
  const ushort_t* bG1 = BT + (size_t)(col0 + srow + 16) * K + skel;
  ushort_t* aL0 = &As[wave * 32][0];
  ushort_t* aL1 = &As[wave * 32 + 16][0];
  ushort_t* bL0 = &Bs[wave * 32][0];
  ushort_t* bL1 = &Bs[wave * 32 + 16][0];

  for (int k0 = 0; k0 < K; k0 += 32) {
    gll16(aG0 + k0, aL0);
    gll16(aG1 + k0, aL1);
    gll16(bG0 + k0, bL0);
    gll16(bG1 + k0, bL1);
    __syncthreads();
    bf16x8_t af[4], bfr[4];
    #pragma unroll
    for (int i = 0; i < 4; ++i) af[i]  = *(const bf16x8_t*)&As[64 * wr + 16 * i + fm][fq * 8];
    #pragma unroll
    for (int j = 0; j < 4; ++j) bfr[j] = *(const bf16x8_t*)&Bs[64 * wc + 16 * j + fm][fq * 8];
    #pragma unroll
    for (int i = 0; i < 4; ++i)
      #pragma unroll
      for (int j = 0; j < 4; ++j)
        acc[i][j] = __builtin_amdgcn_mfma_f32_16x16x32_bf16(af[i], bfr[j], acc[i][j], 0, 0, 0);
    __syncthreads();
  }

  int do_att = (att != nullptr);
  int head = 2 * blockIdx.y + wc;
  float sa[4], sd[4];
  if (do_att) {
    #pragma unroll
    for (int j = 0; j < 4; ++j) {
      int ch = 16 * j + fm;
      sa[j] = bf2f(att[head * CH + ch]);
      sd[j] = bf2f(att[512 + head * CH + ch]);
    }
  }

  // C/D layout: col = lane&15, row = (lane>>4)*4 + reg
  #pragma unroll
  for (int i = 0; i < 4; ++i) {
    int rowb = row0 + 64 * wr + 16 * i + fq * 4;
    #pragma unroll
    for (int r = 0; r < 4; ++r) {
      int row = rowb + r;
      float ss = 0.f, dd = 0.f;
      #pragma unroll
      for (int j = 0; j < 4; ++j) {
        ushort_t uv = f2bf(acc[i][j][r]);
        C[(size_t)row * ldc + col0 + 64 * wc + 16 * j + fm] = uv;
        if (do_att) {
          float cv = bf2f(uv);
          ss += cv * sa[j];
          dd += cv * sd[j];
        }
      }
      if (do_att) {
        #pragma unroll
        for (int off = 8; off > 0; off >>= 1) {
          ss += __shfl_down(ss, off);
          dd += __shfl_down(dd, off);
        }
        if (fm == 0 && row < N_NODES) {
          asrc[row * HEADS + head] = ss;
          dstat[2 * (row * HEADS + head)] = dd;
        }
      }
    }
  }
}

// ---------------- maxless-softmax aggregation (gather per dst), unroll x8 -----
// thread t -> channels (2t, 2t+1), head t>>5.
// mean_mode=0: out[n,512] = bf16(elu(acc + bc) + (x@Wr + br)[n])
// mean_mode=1: out[n,64]  = bf16(elu(mean_h(acc) + bc)); fused node head -> outh
__global__ __launch_bounds__(256) void aggregate(
    const int* __restrict__ rowptr, const int* __restrict__ csr_src,
    const float* __restrict__ asrc, float* __restrict__ dstat,
    const ushort_t* __restrict__ g,
    const void* __restrict__ x, const void* __restrict__ Wr,
    const void* __restrict__ br, const void* __restrict__ bc,
    ushort_t* __restrict__ out, int mean_mode,
    const void* __restrict__ Wo, const void* __restrict__ bo,
    void* __restrict__ outh, const int* __restrict__ dflag)
{
  int isf32 = *dflag;
  __shared__ float sx[3];
  int n = blockIdx.x;
  int t = threadIdx.x;
  if (t < 3) sx[t] = ldf(x, n * 3 + t, isf32);
  __syncthreads();

  int start = rowptr[n], end = rowptr[n + 1];
  int c0 = t * 2;
  int h  = t >> 5;
  int i0 = n * HEADS + h;
  float ad = dstat[2 * i0];

  float l = 0.f, a0 = 0.f, a1 = 0.f;
  int i = start;
  for (; i + 8 <= end; i += 8) {
    int s[8];
    #pragma unroll
    for (int k = 0; k < 8; ++k) s[k] = csr_src[i + k];
    float e[8];
    unsigned int gv[8];
    #pragma unroll
    for (int k = 0; k < 8; ++k) {
      e[k]  = asrc[s[k] * HEADS + h] + ad;
      gv[k] = *(const unsigned int*)(g + (size_t)s[k] * FDIM + c0);
    }
    #pragma unroll
    for (int k = 0; k < 8; ++k) {
      float p = __expf(leakyf(e[k]));
      l  += p;
      a0 += p * bf2f((ushort_t)(gv[k] & 0xffffu));
      a1 += p * bf2f((ushort_t)(gv[k] >> 16));
    }
  }
  for (; i + 2 <= end; i += 2) {
    int s0 = csr_src[i], s1 = csr_src[i + 1];
    float e0 = asrc[s0 * HEADS + h] + ad;
    float e1 = asrc[s1 * HEADS + h] + ad;
    unsigned int g0 = *(const unsigned int*)(g + (size_t)s0 * FDIM + c0);
    unsigned int g1 = *(const unsigned int*)(g + (size_t)s1 * FDIM + c0);
    float p0 = __expf(leakyf(e0)), p1 = __expf(leakyf(e1));
    l  += p0 + p1;
    a0 += p0 * bf2f((ushort_t)(g0 & 0xffffu)) + p1 * bf2f((ushort_t)(g1 & 0xffffu));
    a1 += p0 * bf2f((ushort_t)(g0 >> 16))     + p1 * bf2f((ushort_t)(g1 >> 16));
  }
  if (i < end) {
    int s0 = csr_src[i];
    float p0 = __expf(leakyf(asrc[s0 * HEADS + h] + ad));
    unsigned int g0 = *(const unsigned int*)(g + (size_t)s0 * FDIM + c0);
    l  += p0;
    a0 += p0 * bf2f((ushort_t)(g0 & 0xffffu));
    a1 += p0 * bf2f((ushort_t)(g0 >> 16));
  }
  a0 /= l;
  a1 /= l;
  if ((t & 31) == 0) dstat[2 * i0 + 1] = l;   // sumv, one writer per (node,head)

  if (!mean_mode) {
    float r0 = sx[0] * ldf(Wr, c0, isf32)         + sx[1] * ldf(Wr, 512 + c0, isf32)
             + sx[2] * ldf(Wr, 1024 + c0, isf32)  + ldf(br, c0, isf32);
    float r1 = sx[0] * ldf(Wr, c0 + 1, isf32)     + sx[1] * ldf(Wr, 512 + c0 + 1, isf32)
             + sx[2] * ldf(Wr, 1024 + c0 + 1, isf32) + ldf(br, c0 + 1, isf32);
    unsigned int o0 = f2bf(eluf(a0 + ldf(bc, c0, isf32)) + r0);
    unsigned int o1 = f2bf(eluf(a1 + ldf(bc, c0 + 1, isf32)) + r1);
    *(unsigned int*)(out + (size_t)n * FDIM + c0) = o0 | (o1 << 16);
  } else {
    __shared__ float red[512];
    red[c0] = a0; red[c0 + 1] = a1;
    __syncthreads();
    if (t < 64) {                               // wave 0, uniform branch
      float tot = 0.f;
      #pragma unroll
      for (int hh = 0; hh < 8; ++hh) tot += red[t + 64 * hh];
      float v = eluf(tot * 0.125f + ldf(bc, t, isf32));
      out[(size_t)n * CH + t] = f2bf(v);
      // fused node head: dual butterfly (even lanes -> col0, odd -> col1)
      float p0 = v * ldf(Wo, t * 2 + 0, isf32);
      float p1 = v * ldf(Wo, t * 2 + 1, isf32);
      float vv = (t & 1) ? p1 : p0;
      float ww = (t & 1) ? p0 : p1;
      vv += __shfl_xor(ww, 1);
      #pragma unroll
      for (int off = 2; off < 64; off <<= 1) vv += __shfl_xor(vv, off);
      if (t < 2) stf(outh, (size_t)n * 2 + t, vv + ldf(bo, t, isf32), isf32);
    }
  }
}

// ---------------- edge head: 2-edge pipeline, dual butterfly, packed dstat ----
#define EPW 32
__global__ __launch_bounds__(256) void edge_head3(
    const int* __restrict__ ei, const float* __restrict__ asrc,
    const float* __restrict__ dstat,
    const ushort_t* __restrict__ pq, const void* __restrict__ Wm1,
    const void* __restrict__ bm1, const void* __restrict__ Wm2,
    const void* __restrict__ bm2, void* __restrict__ out,
    const int* __restrict__ dflag)
{
  int isf32 = *dflag;
  int lane = threadIdx.x & 63;
  int c0 = lane * 4;
  float w1r[8][4], w2a[4], w2b[4], b1r[4];
  #pragma unroll
  for (int hh = 0; hh < 8; ++hh)
    #pragma unroll
    for (int j = 0; j < 4; ++j)
      w1r[hh][j] = ldf(Wm1, (64 + hh) * 256 + c0 + j, isf32);
  #pragma unroll
  for (int j = 0; j < 4; ++j) {
    w2a[j] = ldf(Wm2, (c0 + j) * 2 + 0, isf32);
    w2b[j] = ldf(Wm2, (c0 + j) * 2 + 1, isf32);
    b1r[j] = ldf(bm1, c0 + j, isf32);
  }
  float bo0 = ldf(bm2, 0, isf32), bo1 = ldf(bm2, 1, isf32);

  int wid = blockIdx.x * 4 + (threadIdx.x >> 6);
  int e0 = wid * EPW;                       // EPW*4=128 divides N_EDGES exactly
  int h = lane & 7;
  for (int e = e0; e < e0 + EPW; e += 2) {
    int sA = ei[e],     dA = ei[N_EDGES + e];
    int sB = ei[e + 1], dB = ei[N_EDGES + e + 1];
    float2 dsA = *(const float2*)(dstat + 2 * (dA * HEADS + h));
    float2 dsB = *(const float2*)(dstat + 2 * (dB * HEADS + h));
    float vA = asrc[sA * HEADS + h] + dsA.x;
    float vB = asrc[sB * HEADS + h] + dsB.x;
    ushort4 pvA = *(const ushort4*)(pq + (size_t)sA * FDIM + c0);
    ushort4 qvA = *(const ushort4*)(pq + (size_t)dA * FDIM + 256 + c0);
    ushort4 pvB = *(const ushort4*)(pq + (size_t)sB * FDIM + c0);
    ushort4 qvB = *(const ushort4*)(pq + (size_t)dB * FDIM + 256 + c0);
    float aA = __expf(leakyf(vA)) / dsA.y;
    float aB = __expf(leakyf(vB)) / dsB.y;
    float alA[8], alB[8];
    #pragma unroll
    for (int hh = 0; hh < 8; ++hh) { alA[hh] = __shfl(aA, hh); alB[hh] = __shfl(aB, hh); }

    float accA0 = 0.f, accA1 = 0.f, accB0 = 0.f, accB1 = 0.f;
    float pA[4] = { bf2f(pvA.x), bf2f(pvA.y), bf2f(pvA.z), bf2f(pvA.w) };
    float qA[4] = { bf2f(qvA.x), bf2f(qvA.y), bf2f(qvA.z), bf2f(qvA.w) };
    float pB[4] = { bf2f(pvB.x), bf2f(pvB.y), bf2f(pvB.z), bf2f(pvB.w) };
    float qB[4] = { bf2f(qvB.x), bf2f(qvB.y), bf2f(qvB.z), bf2f(qvB.w) };
    #pragma unroll
    for (int j = 0; j < 4; ++j) {
      float hvA = pA[j] + qA[j] + b1r[j];
      float hvB = pB[j] + qB[j] + b1r[j];
      #pragma unroll
      for (int hh = 0; hh < 8; ++hh) {
        hvA += alA[hh] * w1r[hh][j];
        hvB += alB[hh] * w1r[hh][j];
      }
      hvA = fmaxf(hvA, 0.f);
      hvB = fmaxf(hvB, 0.f);
      accA0 += hvA * w2a[j]; accA1 += hvA * w2b[j];
      accB0 += hvB * w2a[j]; accB1 += hvB * w2b[j];
    }
    // dual butterfly: even lanes -> acc0 total, odd lanes -> acc1 total
    float vA2 = (lane & 1) ? accA1 : accA0;
    float wA2 = (lane & 1) ? accA0 : accA1;
    float vB2 = (lane & 1) ? accB1 : accB0;
    float wB2 = (lane & 1) ? accB0 : accB1;
    vA2 += __shfl_xor(wA2, 1);
    vB2 += __shfl_xor(wB2, 1);
    #pragma unroll
    for (int off = 2; off < 64; off <<= 1) {
      vA2 += __shfl_xor(vA2, off);
      vB2 += __shfl_xor(vB2, off);
    }
    if (lane < 2) {
      float bb = lane ? bo1 : bo0;
      stf(out, 100000 + (size_t)e * 2 + lane,       vA2 + bb, isf32);
      stf(out, 100000 + (size_t)(e + 1) * 2 + lane, vB2 + bb, isf32);
    }
  }
}

// ---------------- launch ----------------
extern "C" void kernel_launch(void* const* d_in, const int* in_sizes, int n_in,
                              void* d_out, int out_size, void* d_ws, size_t ws_size,
                              hipStream_t stream) {
  const void* x   = d_in[0];
  const int*  ei  = (const int*)d_in[1];
  const void* Wn  = d_in[4];
  const void* bn  = d_in[5];
  const void* Wr  = d_in[6];
  const void* br  = d_in[7];
  const void* W1  = d_in[8];
  const void* as1 = d_in[9];
  const void* ad1 = d_in[10];
  const void* bc1 = d_in[11];
  const void* W2  = d_in[12];
  const void* as2 = d_in[13];
  const void* ad2 = d_in[14];
  const void* bc2 = d_in[15];
  const void* W3  = d_in[16];
  const void* as3 = d_in[17];
  const void* ad3 = d_in[18];
  const void* bc3 = d_in[19];
  const void* Wo  = d_in[20];
  const void* bo  = d_in[21];
  const void* Wm1 = d_in[22];
  const void* bm1 = d_in[23];
  const void* Wm2 = d_in[24];
  const void* bm2 = d_in[25];

  char* ws = (char*)d_ws;
  size_t off = 0;
  auto take = [&](size_t bytes) -> char* {
    char* p = ws + off;
    off += (bytes + 255) & ~(size_t)255;
    return p;
  };
  ushort_t* h_bf   = (ushort_t*)take((size_t)NPAD * 64 * 2);       // node_embedding
  ushort_t* g_bf   = (ushort_t*)take((size_t)NPAD * FDIM * 2);     // gemm out / P|Q
  ushort_t* o_bf   = (ushort_t*)take((size_t)NPAD * FDIM * 2);     // layer out
  float*    asrc   = (float*)take((size_t)N_NODES * HEADS * 4);
  float*    dstat  = (float*)take((size_t)N_NODES * HEADS * 8);    // {adst, sumv} pairs
  int*      rowptr = (int*)take((size_t)(N_NODES + 1) * 4);
  int*      csr_src= (int*)take((size_t)EPRIME * 4);
  int*      deg    = (int*)take((size_t)N_NODES * 4);
  int*      fillc  = (int*)take((size_t)N_NODES * 4);
  int*      dflag  = (int*)take(256);
  float*    Wfold  = (float*)take((size_t)4 * 512 * 4);            // folded layer-1
  ushort_t* WT2    = (ushort_t*)take((size_t)512 * 512 * 2);       // W2^T  [512][512]
  ushort_t* WT3    = (ushort_t*)take((size_t)512 * 512 * 2);       // W3^T  [512][512]
  ushort_t* WTPQ   = (ushort_t*)take((size_t)512 * 64 * 2);        // [P^T; Q^T] combined
  ushort_t* attv   = (ushort_t*)take((size_t)6 * 512 * 2);         // packed a_src/a_dst x3

  dim3 b256(256);
  const int MB = NPAD / 128;  // 391

  detect_dtype<<<dim3(1), dim3(64), 0, stream>>>(Wn, dflag);

  // weight prep
  fold_w1<<<dim3(2), b256, 0, stream>>>(Wn, bn, W1, Wfold, dflag);
  convert_wt<<<dim3(1024), b256, 0, stream>>>(W2, WT2, 512, 512, 0, dflag);
  convert_wt<<<dim3(1024), b256, 0, stream>>>(W3, WT3, 512, 512, 0, dflag);
  convert_wt<<<dim3(64),   b256, 0, stream>>>(Wm1, WTPQ,            64, 256, 0,  dflag);
  convert_wt<<<dim3(64),   b256, 0, stream>>>(Wm1, WTPQ + 256 * 64, 64, 256, 72, dflag);
  convert_att<<<dim3(12),  b256, 0, stream>>>(as1, ad1, as2, ad2, as3, ad3, attv, dflag);

  // CSR build
  init_deg<<<dim3((N_NODES + 255) / 256), b256, 0, stream>>>(deg, fillc);
  count_edges<<<dim3((N_EDGES + 255) / 256), b256, 0, stream>>>(ei, deg);
  scan64<<<dim3(1), dim3(64), 0, stream>>>(deg, rowptr);
  fill_csr<<<dim3((EPRIME + 255) / 256), b256, 0, stream>>>(ei, rowptr, fillc, csr_src);

  // ---- GAT layer 1: folded x@(Wn@W1), fused attn ----
  encode_g1<<<dim3(N_NODES / 2), b256, 0, stream>>>(x, Wfold, attv, g_bf,
                                                    asrc, dstat, dflag);
  aggregate<<<dim3(N_NODES), b256, 0, stream>>>(rowptr, csr_src, asrc, dstat,
                                                g_bf, x, Wr, br, bc1, o_bf, 0,
                                                nullptr, nullptr, d_out, dflag);

  // ---- GAT layer 2 ----
  gemm_bt<<<dim3(MB, 4), b256, 0, stream>>>(o_bf, WT2, g_bf, 512, 512,
                                            attv + 1024, asrc, dstat);
  aggregate<<<dim3(N_NODES), b256, 0, stream>>>(rowptr, csr_src, asrc, dstat,
                                                g_bf, x, Wr, br, bc2, o_bf, 0,
                                                nullptr, nullptr, d_out, dflag);

  // ---- GAT layer 3 (mean over heads -> ne in h_bf; node head fused) ----
  gemm_bt<<<dim3(MB, 4), b256, 0, stream>>>(o_bf, WT3, g_bf, 512, 512,
                                            attv + 2048, asrc, dstat);
  aggregate<<<dim3(N_NODES), b256, 0, stream>>>(rowptr, csr_src, asrc, dstat,
                                                g_bf, x, Wr, br, bc3, h_bf, 1,
                                                Wo, bo, d_out, dflag);

  // ---- edge head: P|Q in one gemm, then per-edge MLP ----
  gemm_bt<<<dim3(MB, 4), b256, 0, stream>>>(h_bf, WTPQ, g_bf, 64, 512,
                                            nullptr, nullptr, nullptr);
  edge_head3<<<dim3(N_EDGES / (EPW * 4)), b256, 0, stream>>>(ei, asrc, dstat, g_bf,
                                                             Wm1, bm1, Wm2, bm2,
                                                             d_out, dflag);
}

// Round 14
// 1264.329 us; speedup vs baseline: 1.0282x; 1.0282x over previous
//
#include <hip/hip_runtime.h>
#include <hip/hip_bf16.h>
#include <math.h>

#define N_NODES 50000
#define NPAD    50048                  // N_NODES rounded up to 128 (gemm tiles, no guards)
#define N_EDGES 800000
#define EPRIME  (N_EDGES + N_NODES)   // edges + self loops
#define HEADS 8
#define CH 64
#define FDIM 512                       // HEADS*CH

typedef unsigned short ushort_t;
typedef __attribute__((ext_vector_type(8))) short bf16x8_t;  // 8 bf16 = 4 VGPRs
typedef __attribute__((ext_vector_type(4))) float f32x4_t;

__device__ __forceinline__ float bf2f(unsigned short u) {
  union { unsigned int i; float f; } v; v.i = ((unsigned int)u) << 16; return v.f;
}
__device__ __forceinline__ unsigned short f2bf(float f) {
  union { float f; unsigned int i; } v; v.f = f;
  unsigned int x = v.i;
  return (unsigned short)((x + 0x7fffu + ((x >> 16) & 1u)) >> 16);  // RNE
}
__device__ __forceinline__ float ldf(const void* p, size_t idx, int isf32) {
  return isf32 ? ((const float*)p)[idx] : bf2f(((const ushort_t*)p)[idx]);
}
__device__ __forceinline__ void stf(void* p, size_t idx, float v, int isf32) {
  if (isf32) ((float*)p)[idx] = v;
  else       ((ushort_t*)p)[idx] = f2bf(v);
}
__device__ __forceinline__ float leakyf(float v) { return v >= 0.f ? v : 0.2f * v; }
__device__ __forceinline__ float eluf(float v)   { return v > 0.f ? v : expm1f(v); }

// async global->LDS, 16B per lane; LDS dest = wave-uniform base + lane*16
typedef const __attribute__((address_space(1))) unsigned int* gas1_t;
typedef __attribute__((address_space(3))) unsigned int* las3_t;
__device__ __forceinline__ void gll16(const ushort_t* g, ushort_t* l) {
  __builtin_amdgcn_global_load_lds((gas1_t)g, (las3_t)l, 16, 0, 0);
}

// ---------------- dtype detector ----------------
__global__ void detect_dtype(const void* Wn, int* flag) {
  if (blockIdx.x == 0 && threadIdx.x == 0) {
    const ushort_t* u = (const ushort_t*)Wn;
    int extreme = 0;
    for (int i = 0; i < 384; ++i) {
      float v = fabsf(bf2f(u[i]));
      if (v != 0.f && (v > 16.f || v < 6.1e-5f)) extreme++;
    }
    *flag = (extreme >= 20) ? 1 : 0;
  }
}

// ---------------- weight transpose-convert: dst[n*K+k] = src[(boff+k)*N + n] ----
__global__ void convert_wt(const void* __restrict__ src, ushort_t* __restrict__ dst,
                           int K, int N, int boff, const int* __restrict__ dflag) {
  int isf32 = *dflag;
  int tid = blockIdx.x * blockDim.x + threadIdx.x;
  if (tid >= N * K) return;
  int n = tid / K, k = tid % K;
  dst[tid] = f2bf(ldf(src, (size_t)(boff + k) * N + n, isf32));
}

// pack 6 attention vectors (3 layers x {a_src, a_dst}, 512 elems each) to bf16
__global__ void convert_att(const void* s1, const void* d1, const void* s2, const void* d2,
                            const void* s3, const void* d3, ushort_t* __restrict__ dst,
                            const int* __restrict__ dflag) {
  int isf32 = *dflag;
  int tid = blockIdx.x * blockDim.x + threadIdx.x;
  if (tid >= 6 * 512) return;
  int which = tid >> 9, idx = tid & 511;
  const void* p = which == 0 ? s1 : which == 1 ? d1 : which == 2 ? s2
                : which == 3 ? d2 : which == 4 ? s3 : d3;
  dst[tid] = f2bf(ldf(p, idx, isf32));
}

// ---------------- CSR build ----------------
__global__ void init_deg(int* deg, int* fill) {
  int n = blockIdx.x * blockDim.x + threadIdx.x;
  if (n < N_NODES) { deg[n] = 1; fill[n] = 0; }   // 1 = self loop
}

__global__ void count_edges(const int* __restrict__ ei, int* deg) {
  int e = blockIdx.x * blockDim.x + threadIdx.x;
  if (e < N_EDGES) atomicAdd(&deg[ei[N_EDGES + e]], 1);
}

__global__ void scan64(const int* __restrict__ deg, int* __restrict__ rowptr) {
  const int CHUNK = (N_NODES + 63) / 64;   // 782
  int t = threadIdx.x;
  int lo = t * CHUNK;
  int hi = lo + CHUNK; if (hi > N_NODES) hi = N_NODES;
  int s = 0;
  for (int i = lo; i < hi; ++i) s += deg[i];
  int inc = s;
  #pragma unroll
  for (int off = 1; off < 64; off <<= 1) {
    int u = __shfl_up(inc, off);
    if (t >= off) inc += u;
  }
  int run = inc - s;
  for (int i = lo; i < hi; ++i) { rowptr[i] = run; run += deg[i]; }
  if (t == 63) rowptr[N_NODES] = run;
}

__global__ void fill_csr(const int* __restrict__ ei, const int* __restrict__ rowptr,
                         int* fill, int* __restrict__ csr_src) {
  int e = blockIdx.x * blockDim.x + threadIdx.x;
  if (e >= EPRIME) return;
  int s, d;
  if (e < N_EDGES) { s = ei[e]; d = ei[N_EDGES + e]; }
  else             { s = d = e - N_EDGES; }
  int pos = rowptr[d] + atomicAdd(&fill[d], 1);
  csr_src[pos] = s;
}

// ---------------- node encoder ----------------
__global__ void encode_h(const void* __restrict__ x, const void* __restrict__ Wn,
                         const void* __restrict__ bn, ushort_t* __restrict__ h,
                         const int* __restrict__ dflag) {
  int isf32 = *dflag;
  int tid = blockIdx.x * blockDim.x + threadIdx.x;
  if (tid >= N_NODES * 64) return;
  int n = tid >> 6, j = tid & 63;
  float x0 = ldf(x, n * 3 + 0, isf32), x1 = ldf(x, n * 3 + 1, isf32), x2 = ldf(x, n * 3 + 2, isf32);
  float v = x0 * ldf(Wn, j, isf32) + x1 * ldf(Wn, 64 + j, isf32)
          + x2 * ldf(Wn, 128 + j, isf32) + ldf(bn, j, isf32);
  h[tid] = f2bf(v);
}

// ---------------- MFMA GEMM + fused attn-coef epilogue ------------------------
// C = A @ BT^T.  When att != nullptr (layer gemms, 128-col block = 2 heads,
// wave covers exactly one head = 2*by + wc), the epilogue computes
// asrc/adst[row,head] = dot(C_row_head, a_src/a_dst) via 16-lane reduce.
__global__ __launch_bounds__(256) void gemm_bt(
    const ushort_t* __restrict__ A, const ushort_t* __restrict__ BT,
    ushort_t* __restrict__ C, int K, int ldc,
    const ushort_t* __restrict__ att, float* __restrict__ asrc, float* __restrict__ adst)
{
  __shared__ __align__(16) ushort_t As[128][32];
  __shared__ __align__(16) ushort_t Bs[128][32];
  int tid = threadIdx.x;
  int wave = tid >> 6, lane = tid & 63;
  int wr = wave >> 1, wc = wave & 1;
  int row0 = blockIdx.x * 128, col0 = blockIdx.y * 128;
  int fm = lane & 15, fq = lane >> 4;

  f32x4_t acc[4][4];
  #pragma unroll
  for (int i = 0; i < 4; ++i)
    #pragma unroll
    for (int j = 0; j < 4; ++j) acc[i][j] = (f32x4_t){0.f, 0.f, 0.f, 0.f};

  int srow = wave * 32 + (lane >> 2);
  int skel = (lane & 3) * 8;
  const ushort_t* aG0 = A  + (size_t)(row0 + srow) * K + skel;
  const ushort_t* aG1 = A  + (size_t)(row0 + srow + 16) * K + skel;
  const ushort_t* bG0 = BT + (size_t)(col0 + srow) * K + skel;
  const ushort_t* bG1 = BT + (size_t)(col0 + srow + 16) * K + skel;
  ushort_t* aL0 = &As[wave * 32][0];
  ushort_t* aL1 = &As[wave * 32 + 16][0];
  ushort_t* bL0 = &Bs[wave * 32][0];
  ushort_t* bL1 = &Bs[wave * 32 + 16][0];

  for (int k0 = 0; k0 < K; k0 += 32) {
    gll16(aG0 + k0, aL0);
    gll16(aG1 + k0, aL1);
    gll16(bG0 + k0, bL0);
    gll16(bG1 + k0, bL1);
    __syncthreads();
    bf16x8_t af[4], bfr[4];
    #pragma unroll
    for (int i = 0; i < 4; ++i) af[i]  = *(const bf16x8_t*)&As[64 * wr + 16 * i + fm][fq * 8];
    #pragma unroll
    for (int j = 0; j < 4; ++j) bfr[j] = *(const bf16x8_t*)&Bs[64 * wc + 16 * j + fm][fq * 8];
    #pragma unroll
    for (int i = 0; i < 4; ++i)
      #pragma unroll
      for (int j = 0; j < 4; ++j)
        acc[i][j] = __builtin_amdgcn_mfma_f32_16x16x32_bf16(af[i], bfr[j], acc[i][j], 0, 0, 0);
    __syncthreads();
  }

  int do_att = (att != nullptr);
  int head = 2 * blockIdx.y + wc;
  float sa[4], sd[4];
  if (do_att) {
    #pragma unroll
    for (int j = 0; j < 4; ++j) {
      int ch = 16 * j + fm;
      sa[j] = bf2f(att[head * CH + ch]);
      sd[j] = bf2f(att[512 + head * CH + ch]);
    }
  }

  // C/D layout: col = lane&15, row = (lane>>4)*4 + reg
  #pragma unroll
  for (int i = 0; i < 4; ++i) {
    int rowb = row0 + 64 * wr + 16 * i + fq * 4;
    #pragma unroll
    for (int r = 0; r < 4; ++r) {
      int row = rowb + r;
      float ss = 0.f, dd = 0.f;
      #pragma unroll
      for (int j = 0; j < 4; ++j) {
        ushort_t uv = f2bf(acc[i][j][r]);
        C[(size_t)row * ldc + col0 + 64 * wc + 16 * j + fm] = uv;
        if (do_att) {
          float cv = bf2f(uv);
          ss += cv * sa[j];
          dd += cv * sd[j];
        }
      }
      if (do_att) {
        #pragma unroll
        for (int off = 8; off > 0; off >>= 1) {
          ss += __shfl_down(ss, off);
          dd += __shfl_down(dd, off);
        }
        if (fm == 0 && row < N_NODES) {
          asrc[row * HEADS + head] = ss;
          adst[row * HEADS + head] = dd;
        }
      }
    }
  }
}

// ---------------- maxless-softmax aggregation (gather per dst), unroll x8 -----
// thread t -> channels (2t, 2t+1), head t>>5.
// mean_mode=0: out[n,512] = bf16(elu(acc + bc) + (x@Wr + br)[n])
// mean_mode=1: out[n,64]  = bf16(elu(mean_h(acc) + bc)); fused node head -> outh
__global__ __launch_bounds__(256) void aggregate(
    const int* __restrict__ rowptr, const int* __restrict__ csr_src,
    const float* __restrict__ asrc, const float* __restrict__ adst,
    float* __restrict__ sumv,
    const ushort_t* __restrict__ g,
    const void* __restrict__ x, const void* __restrict__ Wr,
    const void* __restrict__ br, const void* __restrict__ bc,
    ushort_t* __restrict__ out, int mean_mode,
    const void* __restrict__ Wo, const void* __restrict__ bo,
    void* __restrict__ outh, const int* __restrict__ dflag)
{
  int isf32 = *dflag;
  __shared__ float sx[3];
  int n = blockIdx.x;
  int t = threadIdx.x;
  if (t < 3) sx[t] = ldf(x, n * 3 + t, isf32);
  __syncthreads();

  int start = rowptr[n], end = rowptr[n + 1];
  int c0 = t * 2;
  int h  = t >> 5;
  int i0 = n * HEADS + h;
  float ad = adst[i0];

  float l = 0.f, a0 = 0.f, a1 = 0.f;
  int i = start;
  for (; i + 8 <= end; i += 8) {
    int s[8];
    #pragma unroll
    for (int k = 0; k < 8; ++k) s[k] = csr_src[i + k];
    float e[8];
    unsigned int gv[8];
    #pragma unroll
    for (int k = 0; k < 8; ++k) {
      e[k]  = asrc[s[k] * HEADS + h] + ad;
      gv[k] = *(const unsigned int*)(g + (size_t)s[k] * FDIM + c0);
    }
    #pragma unroll
    for (int k = 0; k < 8; ++k) {
      float p = __expf(leakyf(e[k]));
      l  += p;
      a0 += p * bf2f((ushort_t)(gv[k] & 0xffffu));
      a1 += p * bf2f((ushort_t)(gv[k] >> 16));
    }
  }
  for (; i + 2 <= end; i += 2) {
    int s0 = csr_src[i], s1 = csr_src[i + 1];
    float e0 = asrc[s0 * HEADS + h] + ad;
    float e1 = asrc[s1 * HEADS + h] + ad;
    unsigned int g0 = *(const unsigned int*)(g + (size_t)s0 * FDIM + c0);
    unsigned int g1 = *(const unsigned int*)(g + (size_t)s1 * FDIM + c0);
    float p0 = __expf(leakyf(e0)), p1 = __expf(leakyf(e1));
    l  += p0 + p1;
    a0 += p0 * bf2f((ushort_t)(g0 & 0xffffu)) + p1 * bf2f((ushort_t)(g1 & 0xffffu));
    a1 += p0 * bf2f((ushort_t)(g0 >> 16))     + p1 * bf2f((ushort_t)(g1 >> 16));
  }
  if (i < end) {
    int s0 = csr_src[i];
    float p0 = __expf(leakyf(asrc[s0 * HEADS + h] + ad));
    unsigned int g0 = *(const unsigned int*)(g + (size_t)s0 * FDIM + c0);
    l  += p0;
    a0 += p0 * bf2f((ushort_t)(g0 & 0xffffu));
    a1 += p0 * bf2f((ushort_t)(g0 >> 16));
  }
  a0 /= l;
  a1 /= l;
  if ((t & 31) == 0) sumv[i0] = l;   // one writer per (node,head)

  if (!mean_mode) {
    float r0 = sx[0] * ldf(Wr, c0, isf32)         + sx[1] * ldf(Wr, 512 + c0, isf32)
             + sx[2] * ldf(Wr, 1024 + c0, isf32)  + ldf(br, c0, isf32);
    float r1 = sx[0] * ldf(Wr, c0 + 1, isf32)     + sx[1] * ldf(Wr, 512 + c0 + 1, isf32)
             + sx[2] * ldf(Wr, 1024 + c0 + 1, isf32) + ldf(br, c0 + 1, isf32);
    unsigned int o0 = f2bf(eluf(a0 + ldf(bc, c0, isf32)) + r0);
    unsigned int o1 = f2bf(eluf(a1 + ldf(bc, c0 + 1, isf32)) + r1);
    *(unsigned int*)(out + (size_t)n * FDIM + c0) = o0 | (o1 << 16);
  } else {
    __shared__ float red[512];
    red[c0] = a0; red[c0 + 1] = a1;
    __syncthreads();
    if (t < 64) {                               // wave 0, uniform branch
      float tot = 0.f;
      #pragma unroll
      for (int hh = 0; hh < 8; ++hh) tot += red[t + 64 * hh];
      ushort_t uv = f2bf(eluf(tot * 0.125f + ldf(bc, t, isf32)));
      out[(size_t)n * CH + t] = uv;
      // fused node head on the bf16-rounded ne value (matches old node_head)
      float nv = bf2f(uv);
      float p0 = nv * ldf(Wo, t * 2 + 0, isf32);
      float p1 = nv * ldf(Wo, t * 2 + 1, isf32);
      float vv = (t & 1) ? p1 : p0;
      float ww = (t & 1) ? p0 : p1;
      vv += __shfl_xor(ww, 1);
      #pragma unroll
      for (int off = 2; off < 64; off <<= 1) vv += __shfl_xor(vv, off);
      if (t < 2) stf(outh, (size_t)n * 2 + t, vv + ldf(bo, t, isf32), isf32);
    }
  }
}

// ---------------- edge head (r12 known-good): 2-edge pipeline -----------------
#define EPW 32
__global__ __launch_bounds__(256) void edge_head3(
    const int* __restrict__ ei, const float* __restrict__ asrc, const float* __restrict__ adst,
    const float* __restrict__ sumv,
    const ushort_t* __restrict__ pq, const void* __restrict__ Wm1,
    const void* __restrict__ bm1, const void* __restrict__ Wm2,
    const void* __restrict__ bm2, void* __restrict__ out,
    const int* __restrict__ dflag)
{
  int isf32 = *dflag;
  int lane = threadIdx.x & 63;
  int c0 = lane * 4;
  float w1r[8][4], w2a[4], w2b[4], b1r[4];
  #pragma unroll
  for (int hh = 0; hh < 8; ++hh)
    #pragma unroll
    for (int j = 0; j < 4; ++j)
      w1r[hh][j] = ldf(Wm1, (64 + hh) * 256 + c0 + j, isf32);
  #pragma unroll
  for (int j = 0; j < 4; ++j) {
    w2a[j] = ldf(Wm2, (c0 + j) * 2 + 0, isf32);
    w2b[j] = ldf(Wm2, (c0 + j) * 2 + 1, isf32);
    b1r[j] = ldf(bm1, c0 + j, isf32);
  }
  float bo0 = ldf(bm2, 0, isf32), bo1 = ldf(bm2, 1, isf32);

  int wid = blockIdx.x * 4 + (threadIdx.x >> 6);
  int e0 = wid * EPW;                       // EPW*4=128 divides N_EDGES exactly
  int h = lane & 7;
  for (int e = e0; e < e0 + EPW; e += 2) {
    int sA = ei[e],     dA = ei[N_EDGES + e];
    int sB = ei[e + 1], dB = ei[N_EDGES + e + 1];
    float vA = asrc[sA * HEADS + h] + adst[dA * HEADS + h];
    float vB = asrc[sB * HEADS + h] + adst[dB * HEADS + h];
    float lA = sumv[dA * HEADS + h], lB = sumv[dB * HEADS + h];
    ushort4 pvA = *(const ushort4*)(pq + (size_t)sA * FDIM + c0);
    ushort4 qvA = *(const ushort4*)(pq + (size_t)dA * FDIM + 256 + c0);
    ushort4 pvB = *(const ushort4*)(pq + (size_t)sB * FDIM + c0);
    ushort4 qvB = *(const ushort4*)(pq + (size_t)dB * FDIM + 256 + c0);
    float aA = __expf(leakyf(vA)) / lA;
    float aB = __expf(leakyf(vB)) / lB;
    float alA[8], alB[8];
    #pragma unroll
    for (int hh = 0; hh < 8; ++hh) { alA[hh] = __shfl(aA, hh); alB[hh] = __shfl(aB, hh); }

    float accA0 = 0.f, accA1 = 0.f, accB0 = 0.f, accB1 = 0.f;
    float pA[4] = { bf2f(pvA.x), bf2f(pvA.y), bf2f(pvA.z), bf2f(pvA.w) };
    float qA[4] = { bf2f(qvA.x), bf2f(qvA.y), bf2f(qvA.z), bf2f(qvA.w) };
    float pB[4] = { bf2f(pvB.x), bf2f(pvB.y), bf2f(pvB.z), bf2f(pvB.w) };
    float qB[4] = { bf2f(qvB.x), bf2f(qvB.y), bf2f(qvB.z), bf2f(qvB.w) };
    #pragma unroll
    for (int j = 0; j < 4; ++j) {
      float hvA = pA[j] + qA[j] + b1r[j];
      float hvB = pB[j] + qB[j] + b1r[j];
      #pragma unroll
      for (int hh = 0; hh < 8; ++hh) {
        hvA += alA[hh] * w1r[hh][j];
        hvB += alB[hh] * w1r[hh][j];
      }
      hvA = fmaxf(hvA, 0.f);
      hvB = fmaxf(hvB, 0.f);
      accA0 += hvA * w2a[j]; accA1 += hvA * w2b[j];
      accB0 += hvB * w2a[j]; accB1 += hvB * w2b[j];
    }
    #pragma unroll
    for (int off = 32; off > 0; off >>= 1) {
      accA0 += __shfl_down(accA0, off);
      accA1 += __shfl_down(accA1, off);
      accB0 += __shfl_down(accB0, off);
      accB1 += __shfl_down(accB1, off);
    }
    if (lane == 0) {
      stf(out, 100000 + (size_t)e * 2 + 0, accA0 + bo0, isf32);
      stf(out, 100000 + (size_t)e * 2 + 1, accA1 + bo1, isf32);
      stf(out, 100000 + (size_t)e * 2 + 2, accB0 + bo0, isf32);
      stf(out, 100000 + (size_t)e * 2 + 3, accB1 + bo1, isf32);
    }
  }
}

// ---------------- launch ----------------
extern "C" void kernel_launch(void* const* d_in, const int* in_sizes, int n_in,
                              void* d_out, int out_size, void* d_ws, size_t ws_size,
                              hipStream_t stream) {
  const void* x   = d_in[0];
  const int*  ei  = (const int*)d_in[1];
  const void* Wn  = d_in[4];
  const void* bn  = d_in[5];
  const void* Wr  = d_in[6];
  const void* br  = d_in[7];
  const void* W1  = d_in[8];
  const void* as1 = d_in[9];
  const void* ad1 = d_in[10];
  const void* bc1 = d_in[11];
  const void* W2  = d_in[12];
  const void* as2 = d_in[13];
  const void* ad2 = d_in[14];
  const void* bc2 = d_in[15];
  const void* W3  = d_in[16];
  const void* as3 = d_in[17];
  const void* ad3 = d_in[18];
  const void* bc3 = d_in[19];
  const void* Wo  = d_in[20];
  const void* bo  = d_in[21];
  const void* Wm1 = d_in[22];
  const void* bm1 = d_in[23];
  const void* Wm2 = d_in[24];
  const void* bm2 = d_in[25];

  char* ws = (char*)d_ws;
  size_t off = 0;
  auto take = [&](size_t bytes) -> char* {
    char* p = ws + off;
    off += (bytes + 255) & ~(size_t)255;
    return p;
  };
  ushort_t* h_bf   = (ushort_t*)take((size_t)NPAD * 64 * 2);       // enc out / node_embedding
  ushort_t* g_bf   = (ushort_t*)take((size_t)NPAD * FDIM * 2);     // gemm out / P|Q
  ushort_t* o_bf   = (ushort_t*)take((size_t)NPAD * FDIM * 2);     // layer out
  float*    asrc   = (float*)take((size_t)N_NODES * HEADS * 4);
  float*    adst   = (float*)take((size_t)N_NODES * HEADS * 4);
  float*    sumv   = (float*)take((size_t)N_NODES * HEADS * 4);
  int*      rowptr = (int*)take((size_t)(N_NODES + 1) * 4);
  int*      csr_src= (int*)take((size_t)EPRIME * 4);
  int*      deg    = (int*)take((size_t)N_NODES * 4);
  int*      fillc  = (int*)take((size_t)N_NODES * 4);
  int*      dflag  = (int*)take(256);
  ushort_t* WT1    = (ushort_t*)take((size_t)512 * 64 * 2);        // W1^T  [512][64]
  ushort_t* WT2    = (ushort_t*)take((size_t)512 * 512 * 2);       // W2^T  [512][512]
  ushort_t* WT3    = (ushort_t*)take((size_t)512 * 512 * 2);       // W3^T  [512][512]
  ushort_t* WTPQ   = (ushort_t*)take((size_t)512 * 64 * 2);        // [P^T ; Q^T] combined
  ushort_t* attv   = (ushort_t*)take((size_t)6 * 512 * 2);         // packed a_src/a_dst x3

  dim3 b256(256);
  const int MB = NPAD / 128;  // 391

  detect_dtype<<<dim3(1), dim3(64), 0, stream>>>(Wn, dflag);

  // weight conversion (transpose to [n][k], bf16); W1 is [64,512] -> K=64
  convert_wt<<<dim3(128),  b256, 0, stream>>>(W1, WT1, 64, 512, 0, dflag);
  convert_wt<<<dim3(1024), b256, 0, stream>>>(W2, WT2, 512, 512, 0, dflag);
  convert_wt<<<dim3(1024), b256, 0, stream>>>(W3, WT3, 512, 512, 0, dflag);
  convert_wt<<<dim3(64),   b256, 0, stream>>>(Wm1, WTPQ,            64, 256, 0,  dflag);
  convert_wt<<<dim3(64),   b256, 0, stream>>>(Wm1, WTPQ + 256 * 64, 64, 256, 72, dflag);
  convert_att<<<dim3(12),  b256, 0, stream>>>(as1, ad1, as2, ad2, as3, ad3, attv, dflag);

  // CSR build
  init_deg<<<dim3((N_NODES + 255) / 256), b256, 0, stream>>>(deg, fillc);
  count_edges<<<dim3((N_EDGES + 255) / 256), b256, 0, stream>>>(ei, deg);
  scan64<<<dim3(1), dim3(64), 0, stream>>>(deg, rowptr);
  fill_csr<<<dim3((EPRIME + 255) / 256), b256, 0, stream>>>(ei, rowptr, fillc, csr_src);

  // node encoder
  encode_h<<<dim3((N_NODES * 64 + 255) / 256), b256, 0, stream>>>(x, Wn, bn, h_bf, dflag);

  // ---- GAT layer 1 (in: h_bf [NPAD,64]); attn fused in gemm epilogue ----
  gemm_bt<<<dim3(MB, 4), b256, 0, stream>>>(h_bf, WT1, g_bf, 64, 512,
                                            attv, asrc, adst);
  aggregate<<<dim3(N_NODES), b256, 0, stream>>>(rowptr, csr_src, asrc, adst, sumv,
                                                g_bf, x, Wr, br, bc1, o_bf, 0,
                                                nullptr, nullptr, d_out, dflag);

  // ---- GAT layer 2 ----
  gemm_bt<<<dim3(MB, 4), b256, 0, stream>>>(o_bf, WT2, g_bf, 512, 512,
                                            attv + 1024, asrc, adst);
  aggregate<<<dim3(N_NODES), b256, 0, stream>>>(rowptr, csr_src, asrc, adst, sumv,
                                                g_bf, x, Wr, br, bc2, o_bf, 0,
                                                nullptr, nullptr, d_out, dflag);

  // ---- GAT layer 3 (mean over heads -> ne in h_bf; node head fused) ----
  gemm_bt<<<dim3(MB, 4), b256, 0, stream>>>(o_bf, WT3, g_bf, 512, 512,
                                            attv + 2048, asrc, adst);
  aggregate<<<dim3(N_NODES), b256, 0, stream>>>(rowptr, csr_src, asrc, adst, sumv,
                                                g_bf, x, Wr, br, bc3, h_bf, 1,
                                                Wo, bo, d_out, dflag);

  // ---- edge head: P|Q in one gemm, then per-edge MLP ----
  gemm_bt<<<dim3(MB, 4), b256, 0, stream>>>(h_bf, WTPQ, g_bf, 64, 512,
                                            nullptr, nullptr, nullptr);
  edge_head3<<<dim3(N_EDGES / (EPW * 4)), b256, 0, stream>>>(ei, asrc, adst, sumv, g_bf,
                                                             Wm1, bm1, Wm2, bm2,
                                                             d_out, dflag);
}